// Round 18
// baseline (294.207 us; speedup 1.0000x reference)
//
#include <hip/hip_runtime.h>
#include <stdint.h>

// ---------- types ----------
typedef __attribute__((ext_vector_type(4))) float f32x4;
typedef __attribute__((ext_vector_type(8))) _Float16 half8;
typedef __attribute__((ext_vector_type(4))) _Float16 half4;
typedef __attribute__((ext_vector_type(2))) unsigned int u32x2;

#define MFMA_F16(a, b, c) __builtin_amdgcn_mfma_f32_16x16x32_f16(a, b, c, 0, 0, 0)
#define MFMA16(a, b, c) __builtin_amdgcn_mfma_f32_16x16x16f16(a, b, c, 0, 0, 0)

#define GLD16(gp, lp)                                                          \
  __builtin_amdgcn_global_load_lds(                                            \
      (const __attribute__((address_space(1))) void*)(gp),                     \
      (__attribute__((address_space(3))) void*)(lp), 16, 0, 0)

__device__ __forceinline__ short f2h(float f) {
  union { _Float16 h; short s; } v;
  v.h = (_Float16)f;  // v_cvt_f16_f32, RNE
  return v.s;
}
__device__ __forceinline__ float exp2_hw(float x) {
  float r;
  asm("v_exp_f32 %0, %1" : "=v"(r) : "v"(x));
  return r;
}
__device__ __forceinline__ uint32_t pkhf(float lo, float hi) {
  uint32_t r;
  asm("v_cvt_pkrtz_f16_f32 %0, %1, %2" : "=v"(r) : "v"(lo), "v"(hi));
  return r;
}

// ---------- fused cast fp32 -> fp16 for all 5 inputs (1 launch) ----------
__global__ __launch_bounds__(256) void cast_all(
    const float* __restrict__ x, const float* __restrict__ wq,
    const float* __restrict__ wk, const float* __restrict__ wv,
    const float* __restrict__ wo, short* __restrict__ Xf,
    short* __restrict__ Wf, short* __restrict__ Wof) {
  const int bid = blockIdx.x;
  const float* src;
  short* dst;
  int lb;
  if (bid < 8192) {
    src = x; dst = Xf; lb = bid;
  } else if (bid < 9216) {
    src = wq; dst = Wf; lb = bid - 8192;
  } else if (bid < 10240) {
    src = wk; dst = Wf + 1048576; lb = bid - 9216;
  } else if (bid < 11264) {
    src = wv; dst = Wf + 2097152; lb = bid - 10240;
  } else {
    src = wo; dst = Wof; lb = bid - 11264;
  }
  const size_t i = (size_t)lb * 256 + threadIdx.x;
  f32x4 v = *reinterpret_cast<const f32x4*>(src + i * 4);
  u32x2 o;
  o[0] = pkhf(v[0], v[1]);
  o[1] = pkhf(v[2], v[3]);
  *reinterpret_cast<u32x2*>(dst + i * 4) = o;
}

// ---------- fused QKV projection GEMM (single-term fp16, BK=64) ----------
// C[m,n] = sum_k X[m,k] * W[n,k],  M=8192, N=3072 (Q|K|V), K=1024.
// grid 1536 linear, XCD-chunked: xcd = L&7 owns 3 consecutive N-columns.
// BK=64: 16 K-steps, LDS [128][64] fp16 x2 (32KB). 128B rows -> row&7
// 8-chunk XOR swizzle. Epilogue: Q (PRE-SCALED by 8*log2e) -> fp16
// [B,H,S,64]; K -> fp16 [B,H,S,64]; V -> fp16 TRANSPOSED [B,H,64,S].
__global__ __launch_bounds__(256) void gemm_proj(
    const short* __restrict__ Xf, const short* __restrict__ Wf,
    short* __restrict__ Qf, short* __restrict__ Kf, short* __restrict__ Vt) {
  __shared__ short sA[128 * 64], sB[128 * 64];
  const int tid = threadIdx.x, lane = tid & 63, w = tid >> 6;
  const int wr = w >> 1, wc = w & 1;
  const int g = lane >> 4, c = lane & 15;
  const int L = blockIdx.x;
  const int xcd = L & 7, idx = L >> 3;
  const int xcol = xcd * 3 + (idx % 3);
  const int yrow = idx / 3;
  const int m0 = yrow * 128, n0 = xcol * 128;

  f32x4 acc[4][4];
#pragma unroll
  for (int i = 0; i < 4; i++)
#pragma unroll
    for (int j = 0; j < 4; j++) acc[i][j] = (f32x4){0.f, 0.f, 0.f, 0.f};

  const int sw0 = ((0 * 4 + g) ^ (c & 7)) * 8;
  const int sw1 = ((1 * 4 + g) ^ (c & 7)) * 8;

  for (int ks = 0; ks < 16; ks++) {
    const int k0 = ks * 64;
    __syncthreads();
#pragma unroll
    for (int i = 0; i < 4; i++) {
      const int ch = i * 256 + tid;
      const int row = ch >> 3;
      const int colg = (ch & 7) ^ (row & 7);  // pre-swizzled global chunk
      const size_t aoff = (size_t)(m0 + row) * 1024 + k0 + colg * 8;
      const size_t boff = (size_t)(n0 + row) * 1024 + k0 + colg * 8;
      GLD16(Xf + aoff, (char*)sA + ch * 16);
      GLD16(Wf + boff, (char*)sB + ch * 16);
    }
    asm volatile("s_waitcnt vmcnt(0)" ::: "memory");
    __syncthreads();

#pragma unroll
    for (int cc = 0; cc < 2; cc++) {
      const int sw = cc ? sw1 : sw0;
      half8 a[4], b8[4];
#pragma unroll
      for (int i = 0; i < 4; i++) {
        a[i] = *(const half8*)&sA[(wr * 64 + i * 16 + c) * 64 + sw];
        b8[i] = *(const half8*)&sB[(wc * 64 + i * 16 + c) * 64 + sw];
      }
#pragma unroll
      for (int i = 0; i < 4; i++)
#pragma unroll
        for (int j = 0; j < 4; j++)
          acc[i][j] = MFMA_F16(a[i], b8[j], acc[i][j]);
    }
  }

  const int section = n0 >> 10;  // 0=Q 1=K 2=V
#pragma unroll
  for (int i = 0; i < 4; i++)
#pragma unroll
    for (int j = 0; j < 4; j++)
#pragma unroll
      for (int r = 0; r < 4; r++) {
        const float v = acc[i][j][r];
        const int m = m0 + wr * 64 + i * 16 + g * 4 + r;
        const int n = n0 + wc * 64 + j * 16 + c;
        const int b = m >> 11, s = m & 2047;
        const int nn = n & 1023;
        const int hh = nn >> 6, d = nn & 63;
        if (section == 0) {
          const size_t off = ((size_t)(b * 16 + hh) * 2048 + s) * 64 + d;
          Qf[off] = f2h(v * 11.5415603271f);
        } else if (section == 1) {
          const size_t off = ((size_t)(b * 16 + hh) * 2048 + s) * 64 + d;
          Kf[off] = f2h(v);
        } else {
          Vt[((size_t)(b * 16 + hh) * 64 + d) * 2048 + s] = f2h(v);
        }
      }
}

// ---------- flash attention ----------
// grid 1024 (XCD-chunked: 8 chunks of 128 = 8 bh x 16 qblk). block = 256
// (4 waves x 32 q-rows = 2 Q-tiles/wave; K/V LDS frags reused across both).
// KVBLK = 64 (32 tiles), double-buffered, vmcnt(0)+barrier per tile.
// launch_bounds(256,4): (256,5) proven catastrophic (48-VGPR spill, R15).
// SWAPPED-OPERAND: QK^T = mfma_16x16x32(K, Q) -> D[k][q], q = lane&15.
// PV uses mfma_16x16x16 per k-slice t (B-frag k = g*4+j matches QK^T's D
// layout -> P stays lane-local, zero cross-lane ops). V A-frags (16x b64)
// are HOISTED right after QK^T so the LDS pipe drains them under the
// softmax VALU chain (T14 issue-early, intra-wave). Softmax in-place on
// sacc (exp2 domain, Q pre-scaled); defer-max THR=8, per-lane check.
// TILE-SKIP at -20. Row-sum l via K=16 ones-MFMA.
__global__ __launch_bounds__(256, 4) void attn_kernel(
    const short* __restrict__ Qf, const short* __restrict__ Kf,
    const short* __restrict__ Vt, short* __restrict__ Z) {
  __shared__ short sK[2][64 * 64];  // fp16 [k-row][d]
  __shared__ short sV[2][64 * 64];  // fp16 [d-row][s]
  const int tid = threadIdx.x, lane = tid & 63, w = tid >> 6;
  const int g = lane >> 4, c = lane & 15;
  const int L = blockIdx.x;
  const int wid = (L & 7) * 128 + (L >> 3);
  const int qblk = wid & 15, bh = wid >> 4;
  const int b = bh >> 4, h = bh & 15;
  const size_t base = (size_t)bh * (2048 * 64);

  // Q fragments per Q-tile qi: lane holds Q[q = c][d = cc*32 + g*8 + j]
  half8 qf[2][2];
  {
    const int qrow = qblk * 128 + w * 32 + c;
#pragma unroll
    for (int qi = 0; qi < 2; qi++)
#pragma unroll
      for (int cc = 0; cc < 2; cc++) {
        const size_t off =
            base + (size_t)(qrow + qi * 16) * 64 + cc * 32 + g * 8;
        qf[qi][cc] = *(const half8*)(Qf + off);
      }
  }

  f32x4 zacc[2][4];  // [qi][dt]: Z[d = dt*16 + g*4 + r][q = c]
  f32x4 lacc[2];     // ones-MFMA row-sum accumulator (elem 0 used)
  float m_run[2] = {-INFINITY, -INFINITY};
#pragma unroll
  for (int qi = 0; qi < 2; qi++) {
    lacc[qi] = (f32x4){0.f, 0.f, 0.f, 0.f};
#pragma unroll
    for (int dt = 0; dt < 4; dt++) zacc[qi][dt] = (f32x4){0.f, 0.f, 0.f, 0.f};
  }

  half4 ones4;
#pragma unroll
  for (int i = 0; i < 4; i++) ones4[i] = (_Float16)1.0f;

  // fragment-read swizzled chunk offsets (128B rows, mask row&7 = c&7)
  const int sw0 = ((0 * 4 + g) ^ (c & 7)) * 8;
  const int sw1 = ((1 * 4 + g) ^ (c & 7)) * 8;

  // staging: 64 rows x 8 chunks = 512 chunks/tile; 2 chunks/thread/array
  const int ch0 = tid, ch1 = tid + 256;
  const int kr0 = ch0 >> 3, kc0 = (ch0 & 7) ^ (kr0 & 7);
  const int kr1 = ch1 >> 3, kc1 = (ch1 & 7) ^ (kr1 & 7);
  const int kofs0 = kr0 * 64 + kc0 * 8, kofs1 = kr1 * 64 + kc1 * 8;
  const int vofs0 = kr0 * 2048 + kc0 * 8, vofs1 = kr1 * 2048 + kc1 * 8;
  const int ldo0 = ch0 * 16, ldo1 = ch1 * 16;

  auto stage = [&](int buf, int kt) {
    const size_t kb = base + (size_t)kt * 4096;
    const size_t vb = base + (size_t)kt * 64;
    GLD16(Kf + kb + kofs0, (char*)&sK[buf][0] + ldo0);
    GLD16(Kf + kb + kofs1, (char*)&sK[buf][0] + ldo1);
    GLD16(Vt + vb + vofs0, (char*)&sV[buf][0] + ldo0);
    GLD16(Vt + vb + vofs1, (char*)&sV[buf][0] + ldo1);
  };

  auto compute = [&](int buf) {
    // QK^T swapped: D[k][q]; lane: q=c, k=t*16+g*4+r. K-frags reused by qi.
    f32x4 sacc[2][4];
#pragma unroll
    for (int qi = 0; qi < 2; qi++)
#pragma unroll
      for (int t = 0; t < 4; t++) sacc[qi][t] = (f32x4){0.f, 0.f, 0.f, 0.f};
    __builtin_amdgcn_s_setprio(1);
#pragma unroll
    for (int cc = 0; cc < 2; cc++) {
      const int sw = cc ? sw1 : sw0;
#pragma unroll
      for (int t = 0; t < 4; t++) {
        const int kr = (t * 16 + c) * 64 + sw;
        half8 k8 = *(const half8*)&sK[buf][kr];
        sacc[0][t] = MFMA_F16(k8, qf[0][cc], sacc[0][t]);
        sacc[1][t] = MFMA_F16(k8, qf[1][cc], sacc[1][t]);
      }
    }
    __builtin_amdgcn_s_setprio(0);

    // HOIST all 16 V A-fragments now: LDS pipe drains them while the
    // softmax VALU chain below runs (intra-wave overlap).
    half4 va[4][4];
#pragma unroll
    for (int t = 0; t < 4; t++) {
      const int vo = ((2 * t + (g >> 1)) ^ (c & 7)) * 8 + (g & 1) * 4;
#pragma unroll
      for (int dt = 0; dt < 4; dt++)
        va[t][dt] = *(const half4*)&sV[buf][(dt * 16 + c) * 64 + vo];
    }

    // per-lane max via v_max3 chains (cross-lane only in rescale branch)
    float mxl0, mxl1;
    {
      float m = fmaxf(sacc[0][0][0], sacc[0][0][1]);
      m = fmaxf(fmaxf(m, sacc[0][0][2]), sacc[0][0][3]);
      m = fmaxf(fmaxf(m, sacc[0][1][0]), sacc[0][1][1]);
      m = fmaxf(fmaxf(m, sacc[0][1][2]), sacc[0][1][3]);
      m = fmaxf(fmaxf(m, sacc[0][2][0]), sacc[0][2][1]);
      m = fmaxf(fmaxf(m, sacc[0][2][2]), sacc[0][2][3]);
      m = fmaxf(fmaxf(m, sacc[0][3][0]), sacc[0][3][1]);
      mxl0 = fmaxf(fmaxf(m, sacc[0][3][2]), sacc[0][3][3]);
    }
    {
      float m = fmaxf(sacc[1][0][0], sacc[1][0][1]);
      m = fmaxf(fmaxf(m, sacc[1][0][2]), sacc[1][0][3]);
      m = fmaxf(fmaxf(m, sacc[1][1][0]), sacc[1][1][1]);
      m = fmaxf(fmaxf(m, sacc[1][1][2]), sacc[1][1][3]);
      m = fmaxf(fmaxf(m, sacc[1][2][0]), sacc[1][2][1]);
      m = fmaxf(fmaxf(m, sacc[1][2][2]), sacc[1][2][3]);
      m = fmaxf(fmaxf(m, sacc[1][3][0]), sacc[1][3][1]);
      mxl1 = fmaxf(fmaxf(m, sacc[1][3][2]), sacc[1][3][3]);
    }
    const float grow = fmaxf(mxl0 - m_run[0], mxl1 - m_run[1]);
    // TILE-SKIP (exact): whole tile negligible
    if (!__any(grow > -20.0f)) return;
    // defer-max: rescale only when some row grew by > 8 (log2 units)
    if (__any(grow > 8.0f)) {
      float mx0 = fmaxf(mxl0, __shfl_xor(mxl0, 16));
      mx0 = fmaxf(mx0, __shfl_xor(mx0, 32));
      float mx1 = fmaxf(mxl1, __shfl_xor(mxl1, 16));
      mx1 = fmaxf(mx1, __shfl_xor(mx1, 32));
#pragma unroll
      for (int qi = 0; qi < 2; qi++) {
        const float mnew = fmaxf(m_run[qi], qi ? mx1 : mx0);
        const float sc = exp2_hw(m_run[qi] - mnew);
        m_run[qi] = mnew;
#pragma unroll
        for (int r = 0; r < 4; r++) lacc[qi][r] *= sc;
#pragma unroll
        for (int dt = 0; dt < 4; dt++)
#pragma unroll
          for (int r = 0; r < 4; r++) zacc[qi][dt][r] *= sc;
      }
    }
    // in-place exp2 on sacc
#pragma unroll
    for (int t = 0; t < 4; t++)
#pragma unroll
      for (int r = 0; r < 4; r++) {
        sacc[0][t][r] = exp2_hw(sacc[0][t][r] - m_run[0]);
        sacc[1][t][r] = exp2_hw(sacc[1][t][r] - m_run[1]);
      }

    // PV via K=16 MFMA per k-slice t: B-frag = lane's own packed P words.
    __builtin_amdgcn_s_setprio(1);
#pragma unroll
    for (int t = 0; t < 4; t++) {
      union { u32x2 u; half4 h; } b0, b1;
      b0.u[0] = pkhf(sacc[0][t][0], sacc[0][t][1]);
      b0.u[1] = pkhf(sacc[0][t][2], sacc[0][t][3]);
      b1.u[0] = pkhf(sacc[1][t][0], sacc[1][t][1]);
      b1.u[1] = pkhf(sacc[1][t][2], sacc[1][t][3]);
      lacc[0] = MFMA16(ones4, b0.h, lacc[0]);
      lacc[1] = MFMA16(ones4, b1.h, lacc[1]);
#pragma unroll
      for (int dt = 0; dt < 4; dt++) {
        zacc[0][dt] = MFMA16(va[t][dt], b0.h, zacc[0][dt]);
        zacc[1][dt] = MFMA16(va[t][dt], b1.h, zacc[1][dt]);
      }
    }
    __builtin_amdgcn_s_setprio(0);
  };

  // prologue
  stage(0, 0);
  asm volatile("s_waitcnt vmcnt(0)" ::: "memory");
  __builtin_amdgcn_s_barrier();

  // 32 tiles, double-buffered 2-step unroll
#pragma unroll 1
  for (int t2 = 0; t2 < 16; t2++) {
    {
      stage(1, 2 * t2 + 1);
      compute(0);
      asm volatile("s_waitcnt vmcnt(0) lgkmcnt(0)" ::: "memory");
      __builtin_amdgcn_s_barrier();
    }
    {
      const int nxt = 2 * t2 + 2;
      stage(0, nxt < 32 ? nxt : 31);  // clamp (last restages 31, unused)
      compute(1);
      asm volatile("s_waitcnt vmcnt(0) lgkmcnt(0)" ::: "memory");
      __builtin_amdgcn_s_barrier();
    }
  }

  // epilogue: lacc[qi][0] already holds the full row sum (MFMA k-reduce)
  const int qg0 = qblk * 128 + w * 32 + c;
#pragma unroll
  for (int qi = 0; qi < 2; qi++) {
    const float rs = lacc[qi][0];
    const float inv = rs > 0.f ? 1.0f / rs : 0.f;
    const int qg = qg0 + qi * 16;
#pragma unroll
    for (int dt = 0; dt < 4; dt++) {
      u32x2 zw;
      zw[0] = pkhf(zacc[qi][dt][0] * inv, zacc[qi][dt][1] * inv);
      zw[1] = pkhf(zacc[qi][dt][2] * inv, zacc[qi][dt][3] * inv);
      *reinterpret_cast<u32x2*>(
          &Z[(size_t)(b * 2048 + qg) * 1024 + h * 64 + dt * 16 + g * 4]) = zw;
    }
  }
}

// ---------- output projection GEMM (fp16, BK=64) ----------
// out[m,n] = sum_k Z[m,k]*Wo[n,k] + bo[n]. grid 512 linear, XCD-swizzled.
__global__ __launch_bounds__(256) void gemm_out(
    const short* __restrict__ Zb, const short* __restrict__ Wof,
    const float* __restrict__ bo, float* __restrict__ out) {
  __shared__ short sA[128 * 64], sB[128 * 64];
  const int tid = threadIdx.x, lane = tid & 63, w = tid >> 6;
  const int wr = w >> 1, wc = w & 1;
  const int g = lane >> 4, c = lane & 15;
  const int L = blockIdx.x;
  const int m0 = (L >> 3) * 128, n0 = (L & 7) * 128;

  f32x4 acc[4][4];
#pragma unroll
  for (int i = 0; i < 4; i++)
#pragma unroll
    for (int j = 0; j < 4; j++) acc[i][j] = (f32x4){0.f, 0.f, 0.f, 0.f};

  const int sw0 = ((0 * 4 + g) ^ (c & 7)) * 8;
  const int sw1 = ((1 * 4 + g) ^ (c & 7)) * 8;

  for (int ks = 0; ks < 16; ks++) {
    const int k0 = ks * 64;
    __syncthreads();
#pragma unroll
    for (int i = 0; i < 4; i++) {
      const int ch = i * 256 + tid;
      const int row = ch >> 3;
      const int colg = (ch & 7) ^ (row & 7);
      const size_t aoff = (size_t)(m0 + row) * 1024 + k0 + colg * 8;
      const size_t boff = (size_t)(n0 + row) * 1024 + k0 + colg * 8;
      GLD16(Zb + aoff, (char*)sA + ch * 16);
      GLD16(Wof + boff, (char*)sB + ch * 16);
    }
    asm volatile("s_waitcnt vmcnt(0)" ::: "memory");
    __syncthreads();

#pragma unroll
    for (int cc = 0; cc < 2; cc++) {
      const int sw = cc ? sw1 : sw0;
      half8 a[4], b8[4];
#pragma unroll
      for (int i = 0; i < 4; i++) {
        a[i] = *(const half8*)&sA[(wr * 64 + i * 16 + c) * 64 + sw];
        b8[i] = *(const half8*)&sB[(wc * 64 + i * 16 + c) * 64 + sw];
      }
#pragma unroll
      for (int i = 0; i < 4; i++)
#pragma unroll
        for (int j = 0; j < 4; j++)
          acc[i][j] = MFMA_F16(a[i], b8[j], acc[i][j]);
    }
  }

#pragma unroll
  for (int i = 0; i < 4; i++)
#pragma unroll
    for (int j = 0; j < 4; j++)
#pragma unroll
      for (int r = 0; r < 4; r++) {
        const int m = m0 + wr * 64 + i * 16 + g * 4 + r;
        const int n = n0 + wc * 64 + j * 16 + c;
        out[(size_t)m * 1024 + n] = acc[i][j][r] + bo[n];
      }
}

// ---------- host ----------
extern "C" void kernel_launch(void* const* d_in, const int* in_sizes, int n_in,
                              void* d_out, int out_size, void* d_ws, size_t ws_size,
                              hipStream_t stream) {
  const float* x  = (const float*)d_in[0];
  const float* Wq = (const float*)d_in[1];
  const float* Wk = (const float*)d_in[2];
  const float* Wv = (const float*)d_in[3];
  const float* Wo = (const float*)d_in[4];
  const float* bo = (const float*)d_in[5];
  float* out = (float*)d_out;

  const size_t NX = 8388608;   // B*S*D_MODEL
  const size_t NW = 1048576;   // per-projection weight elements
  const size_t NQ = 8388608;   // B*H*S*D_K

  char* p = (char*)d_ws;
  auto take = [&](size_t bytes) -> char* {
    char* r = p;
    p += (bytes + 255) & ~(size_t)255;
    return r;
  };
  short* Xf  = (short*)take(NX * 2);
  short* Wf  = (short*)take(3 * NW * 2);
  short* Wof = (short*)take(NW * 2);
  short* Qf  = (short*)take(NQ * 2);
  short* Kf  = (short*)take(NQ * 2);
  short* Vt  = (short*)take(NQ * 2);
  short* Zb  = (short*)take(NQ * 2);

  cast_all<<<dim3(12288), 256, 0, stream>>>(x, Wq, Wk, Wv, Wo, Xf, Wf, Wof);
  gemm_proj<<<dim3(1536), 256, 0, stream>>>(Xf, Wf, Qf, Kf, Vt);
  attn_kernel<<<dim3(1024), 256, 0, stream>>>(Qf, Kf, Vt, Zb);
  gemm_out<<<dim3(512), 256, 0, stream>>>(Zb, Wof, bo, out);
}

// Round 19
// 232.750 us; speedup vs baseline: 1.2640x; 1.2640x over previous
//
#include <hip/hip_runtime.h>
#include <stdint.h>

// ---------- types ----------
typedef __attribute__((ext_vector_type(4))) float f32x4;
typedef __attribute__((ext_vector_type(8))) _Float16 half8;
typedef __attribute__((ext_vector_type(4))) _Float16 half4;
typedef __attribute__((ext_vector_type(2))) unsigned int u32x2;

#define MFMA_F16(a, b, c) __builtin_amdgcn_mfma_f32_16x16x32_f16(a, b, c, 0, 0, 0)
#define MFMA16(a, b, c) __builtin_amdgcn_mfma_f32_16x16x16f16(a, b, c, 0, 0, 0)

#define GLD16(gp, lp)                                                          \
  __builtin_amdgcn_global_load_lds(                                            \
      (const __attribute__((address_space(1))) void*)(gp),                     \
      (__attribute__((address_space(3))) void*)(lp), 16, 0, 0)

__device__ __forceinline__ short f2h(float f) {
  union { _Float16 h; short s; } v;
  v.h = (_Float16)f;  // v_cvt_f16_f32, RNE
  return v.s;
}
__device__ __forceinline__ float exp2_hw(float x) {
  float r;
  asm("v_exp_f32 %0, %1" : "=v"(r) : "v"(x));
  return r;
}
__device__ __forceinline__ uint32_t pkhf(float lo, float hi) {
  uint32_t r;
  asm("v_cvt_pkrtz_f16_f32 %0, %1, %2" : "=v"(r) : "v"(lo), "v"(hi));
  return r;
}

// ---------- fused cast fp32 -> fp16 for all 5 inputs (1 launch) ----------
__global__ __launch_bounds__(256) void cast_all(
    const float* __restrict__ x, const float* __restrict__ wq,
    const float* __restrict__ wk, const float* __restrict__ wv,
    const float* __restrict__ wo, short* __restrict__ Xf,
    short* __restrict__ Wf, short* __restrict__ Wof) {
  const int bid = blockIdx.x;
  const float* src;
  short* dst;
  int lb;
  if (bid < 8192) {
    src = x; dst = Xf; lb = bid;
  } else if (bid < 9216) {
    src = wq; dst = Wf; lb = bid - 8192;
  } else if (bid < 10240) {
    src = wk; dst = Wf + 1048576; lb = bid - 9216;
  } else if (bid < 11264) {
    src = wv; dst = Wf + 2097152; lb = bid - 10240;
  } else {
    src = wo; dst = Wof; lb = bid - 11264;
  }
  const size_t i = (size_t)lb * 256 + threadIdx.x;
  f32x4 v = *reinterpret_cast<const f32x4*>(src + i * 4);
  u32x2 o;
  o[0] = pkhf(v[0], v[1]);
  o[1] = pkhf(v[2], v[3]);
  *reinterpret_cast<u32x2*>(dst + i * 4) = o;
}

// ---------- fused QKV projection GEMM (single-term fp16, BK=64) ----------
// C[m,n] = sum_k X[m,k] * W[n,k],  M=8192, N=3072 (Q|K|V), K=1024.
// grid 1536 linear, XCD-chunked: xcd = L&7 owns 3 consecutive N-columns.
// BK=64: 16 K-steps, LDS [128][64] fp16 x2 (32KB). 128B rows -> row&7
// 8-chunk XOR swizzle. Epilogue: Q (PRE-SCALED by 8*log2e) -> fp16
// [B,H,S,64]; K -> fp16 [B,H,S,64]; V -> fp16 TRANSPOSED [B,H,64,S].
__global__ __launch_bounds__(256) void gemm_proj(
    const short* __restrict__ Xf, const short* __restrict__ Wf,
    short* __restrict__ Qf, short* __restrict__ Kf, short* __restrict__ Vt) {
  __shared__ short sA[128 * 64], sB[128 * 64];
  const int tid = threadIdx.x, lane = tid & 63, w = tid >> 6;
  const int wr = w >> 1, wc = w & 1;
  const int g = lane >> 4, c = lane & 15;
  const int L = blockIdx.x;
  const int xcd = L & 7, idx = L >> 3;
  const int xcol = xcd * 3 + (idx % 3);
  const int yrow = idx / 3;
  const int m0 = yrow * 128, n0 = xcol * 128;

  f32x4 acc[4][4];
#pragma unroll
  for (int i = 0; i < 4; i++)
#pragma unroll
    for (int j = 0; j < 4; j++) acc[i][j] = (f32x4){0.f, 0.f, 0.f, 0.f};

  const int sw0 = ((0 * 4 + g) ^ (c & 7)) * 8;
  const int sw1 = ((1 * 4 + g) ^ (c & 7)) * 8;

  for (int ks = 0; ks < 16; ks++) {
    const int k0 = ks * 64;
    __syncthreads();
#pragma unroll
    for (int i = 0; i < 4; i++) {
      const int ch = i * 256 + tid;
      const int row = ch >> 3;
      const int colg = (ch & 7) ^ (row & 7);  // pre-swizzled global chunk
      const size_t aoff = (size_t)(m0 + row) * 1024 + k0 + colg * 8;
      const size_t boff = (size_t)(n0 + row) * 1024 + k0 + colg * 8;
      GLD16(Xf + aoff, (char*)sA + ch * 16);
      GLD16(Wf + boff, (char*)sB + ch * 16);
    }
    asm volatile("s_waitcnt vmcnt(0)" ::: "memory");
    __syncthreads();

#pragma unroll
    for (int cc = 0; cc < 2; cc++) {
      const int sw = cc ? sw1 : sw0;
      half8 a[4], b8[4];
#pragma unroll
      for (int i = 0; i < 4; i++) {
        a[i] = *(const half8*)&sA[(wr * 64 + i * 16 + c) * 64 + sw];
        b8[i] = *(const half8*)&sB[(wc * 64 + i * 16 + c) * 64 + sw];
      }
#pragma unroll
      for (int i = 0; i < 4; i++)
#pragma unroll
        for (int j = 0; j < 4; j++)
          acc[i][j] = MFMA_F16(a[i], b8[j], acc[i][j]);
    }
  }

  const int section = n0 >> 10;  // 0=Q 1=K 2=V
#pragma unroll
  for (int i = 0; i < 4; i++)
#pragma unroll
    for (int j = 0; j < 4; j++)
#pragma unroll
      for (int r = 0; r < 4; r++) {
        const float v = acc[i][j][r];
        const int m = m0 + wr * 64 + i * 16 + g * 4 + r;
        const int n = n0 + wc * 64 + j * 16 + c;
        const int b = m >> 11, s = m & 2047;
        const int nn = n & 1023;
        const int hh = nn >> 6, d = nn & 63;
        if (section == 0) {
          const size_t off = ((size_t)(b * 16 + hh) * 2048 + s) * 64 + d;
          Qf[off] = f2h(v * 11.5415603271f);
        } else if (section == 1) {
          const size_t off = ((size_t)(b * 16 + hh) * 2048 + s) * 64 + d;
          Kf[off] = f2h(v);
        } else {
          Vt[((size_t)(b * 16 + hh) * 64 + d) * 2048 + s] = f2h(v);
        }
      }
}

// ---------- flash attention (R17 state — session best) ----------
// grid 1024 (XCD-chunked: 8 chunks of 128 = 8 bh x 16 qblk). block = 256
// (4 waves x 32 q-rows = 2 Q-tiles/wave; K/V LDS frags reused across both).
// KVBLK = 64 (32 tiles), double-buffered, vmcnt(0)+barrier per tile.
// launch_bounds(256,4): (256,5) proven catastrophic (48-VGPR spill, R15);
// hoisting all 16 V-frags across the softmax also spills (R18: FETCH
// 25MB->93MB). Keep V reads inline in the PV loop — TLP hides them.
// SWAPPED-OPERAND: QK^T = mfma_16x16x32(K, Q) -> D[k][q], q = lane&15.
// PV uses mfma_16x16x16 per k-slice t: its B-fragment layout (k = g*4+j)
// EXACTLY matches QK^T's D output (k = t*16+g*4+r) -> P stays lane-local,
// zero cross-lane ops. V A-frags are b64 reads at swizzled chunk
// (2t+(g>>1))^(c&7) (<=2-way banks, free). Softmax in-register (Q
// pre-scaled, exp2 domain); defer-max THR=8 per-lane check. TILE-SKIP at
// -20. Row-sum l via K=16 ones-MFMA.
__global__ __launch_bounds__(256, 4) void attn_kernel(
    const short* __restrict__ Qf, const short* __restrict__ Kf,
    const short* __restrict__ Vt, short* __restrict__ Z) {
  __shared__ short sK[2][64 * 64];  // fp16 [k-row][d]
  __shared__ short sV[2][64 * 64];  // fp16 [d-row][s]
  const int tid = threadIdx.x, lane = tid & 63, w = tid >> 6;
  const int g = lane >> 4, c = lane & 15;
  const int L = blockIdx.x;
  const int wid = (L & 7) * 128 + (L >> 3);
  const int qblk = wid & 15, bh = wid >> 4;
  const int b = bh >> 4, h = bh & 15;
  const size_t base = (size_t)bh * (2048 * 64);

  // Q fragments per Q-tile qi: lane holds Q[q = c][d = cc*32 + g*8 + j]
  half8 qf[2][2];
  {
    const int qrow = qblk * 128 + w * 32 + c;
#pragma unroll
    for (int qi = 0; qi < 2; qi++)
#pragma unroll
      for (int cc = 0; cc < 2; cc++) {
        const size_t off =
            base + (size_t)(qrow + qi * 16) * 64 + cc * 32 + g * 8;
        qf[qi][cc] = *(const half8*)(Qf + off);
      }
  }

  f32x4 zacc[2][4];  // [qi][dt]: Z[d = dt*16 + g*4 + r][q = c]
  f32x4 lacc[2];     // ones-MFMA row-sum accumulator (elem 0 used)
  float m_run[2] = {-INFINITY, -INFINITY};
#pragma unroll
  for (int qi = 0; qi < 2; qi++) {
    lacc[qi] = (f32x4){0.f, 0.f, 0.f, 0.f};
#pragma unroll
    for (int dt = 0; dt < 4; dt++) zacc[qi][dt] = (f32x4){0.f, 0.f, 0.f, 0.f};
  }

  half4 ones4;
#pragma unroll
  for (int i = 0; i < 4; i++) ones4[i] = (_Float16)1.0f;

  // fragment-read swizzled chunk offsets (128B rows, mask row&7 = c&7)
  const int sw0 = ((0 * 4 + g) ^ (c & 7)) * 8;
  const int sw1 = ((1 * 4 + g) ^ (c & 7)) * 8;

  // staging: 64 rows x 8 chunks = 512 chunks/tile; 2 chunks/thread/array
  const int ch0 = tid, ch1 = tid + 256;
  const int kr0 = ch0 >> 3, kc0 = (ch0 & 7) ^ (kr0 & 7);
  const int kr1 = ch1 >> 3, kc1 = (ch1 & 7) ^ (kr1 & 7);
  const int kofs0 = kr0 * 64 + kc0 * 8, kofs1 = kr1 * 64 + kc1 * 8;
  const int vofs0 = kr0 * 2048 + kc0 * 8, vofs1 = kr1 * 2048 + kc1 * 8;
  const int ldo0 = ch0 * 16, ldo1 = ch1 * 16;

  auto stage = [&](int buf, int kt) {
    const size_t kb = base + (size_t)kt * 4096;
    const size_t vb = base + (size_t)kt * 64;
    GLD16(Kf + kb + kofs0, (char*)&sK[buf][0] + ldo0);
    GLD16(Kf + kb + kofs1, (char*)&sK[buf][0] + ldo1);
    GLD16(Vt + vb + vofs0, (char*)&sV[buf][0] + ldo0);
    GLD16(Vt + vb + vofs1, (char*)&sV[buf][0] + ldo1);
  };

  auto compute = [&](int buf) {
    // QK^T swapped: D[k][q]; lane: q=c, k=t*16+g*4+r. K-frags reused by qi.
    f32x4 sacc[2][4];
#pragma unroll
    for (int qi = 0; qi < 2; qi++)
#pragma unroll
      for (int t = 0; t < 4; t++) sacc[qi][t] = (f32x4){0.f, 0.f, 0.f, 0.f};
    __builtin_amdgcn_s_setprio(1);
#pragma unroll
    for (int cc = 0; cc < 2; cc++) {
      const int sw = cc ? sw1 : sw0;
#pragma unroll
      for (int t = 0; t < 4; t++) {
        const int kr = (t * 16 + c) * 64 + sw;
        half8 k8 = *(const half8*)&sK[buf][kr];
        sacc[0][t] = MFMA_F16(k8, qf[0][cc], sacc[0][t]);
        sacc[1][t] = MFMA_F16(k8, qf[1][cc], sacc[1][t]);
      }
    }
    __builtin_amdgcn_s_setprio(0);

    // per-q-tile softmax (exp2 domain, pre-scaled Q, no zero-mask)
    float p0[16], p1[16];
#pragma unroll
    for (int t = 0; t < 4; t++)
#pragma unroll
      for (int r = 0; r < 4; r++) {
        p0[t * 4 + r] = sacc[0][t][r];
        p1[t * 4 + r] = sacc[1][t][r];
      }
    // per-lane max via v_max3 chains (cross-lane only in rescale branch)
    float mxl0, mxl1;
    {
      float m = fmaxf(p0[0], p0[1]);
      m = fmaxf(fmaxf(m, p0[2]), p0[3]);
      m = fmaxf(fmaxf(m, p0[4]), p0[5]);
      m = fmaxf(fmaxf(m, p0[6]), p0[7]);
      m = fmaxf(fmaxf(m, p0[8]), p0[9]);
      m = fmaxf(fmaxf(m, p0[10]), p0[11]);
      m = fmaxf(fmaxf(m, p0[12]), p0[13]);
      mxl0 = fmaxf(fmaxf(m, p0[14]), p0[15]);
    }
    {
      float m = fmaxf(p1[0], p1[1]);
      m = fmaxf(fmaxf(m, p1[2]), p1[3]);
      m = fmaxf(fmaxf(m, p1[4]), p1[5]);
      m = fmaxf(fmaxf(m, p1[6]), p1[7]);
      m = fmaxf(fmaxf(m, p1[8]), p1[9]);
      m = fmaxf(fmaxf(m, p1[10]), p1[11]);
      m = fmaxf(fmaxf(m, p1[12]), p1[13]);
      mxl1 = fmaxf(fmaxf(m, p1[14]), p1[15]);
    }
    const float grow = fmaxf(mxl0 - m_run[0], mxl1 - m_run[1]);
    // TILE-SKIP (exact): whole tile negligible
    if (!__any(grow > -20.0f)) return;
    // defer-max: rescale only when some row grew by > 8 (log2 units)
    if (__any(grow > 8.0f)) {
      float mx0 = fmaxf(mxl0, __shfl_xor(mxl0, 16));
      mx0 = fmaxf(mx0, __shfl_xor(mx0, 32));
      float mx1 = fmaxf(mxl1, __shfl_xor(mxl1, 16));
      mx1 = fmaxf(mx1, __shfl_xor(mx1, 32));
#pragma unroll
      for (int qi = 0; qi < 2; qi++) {
        const float mnew = fmaxf(m_run[qi], qi ? mx1 : mx0);
        const float sc = exp2_hw(m_run[qi] - mnew);
        m_run[qi] = mnew;
#pragma unroll
        for (int r = 0; r < 4; r++) lacc[qi][r] *= sc;
#pragma unroll
        for (int dt = 0; dt < 4; dt++)
#pragma unroll
          for (int r = 0; r < 4; r++) zacc[qi][dt][r] *= sc;
      }
    }
#pragma unroll
    for (int i = 0; i < 16; i++) {
      p0[i] = exp2_hw(p0[i] - m_run[0]);
      p1[i] = exp2_hw(p1[i] - m_run[1]);
    }

    // PV via K=16 MFMA per k-slice t: B-frag = lane's own packed P words
    // (k = t*16 + g*4 + j matches the 16x16x16 operand layout k = g*4+j).
    // A-frag = V b64 read: Vt[d = dt*16+c][k-col t*16+g*4], swizzled chunk
    // (2t+(g>>1))^(c&7), sub-offset (g&1)*4 shorts.
    __builtin_amdgcn_s_setprio(1);
#pragma unroll
    for (int t = 0; t < 4; t++) {
      union { u32x2 u; half4 h; } b0, b1;
      b0.u[0] = pkhf(p0[4 * t + 0], p0[4 * t + 1]);
      b0.u[1] = pkhf(p0[4 * t + 2], p0[4 * t + 3]);
      b1.u[0] = pkhf(p1[4 * t + 0], p1[4 * t + 1]);
      b1.u[1] = pkhf(p1[4 * t + 2], p1[4 * t + 3]);
      lacc[0] = MFMA16(ones4, b0.h, lacc[0]);
      lacc[1] = MFMA16(ones4, b1.h, lacc[1]);
      const int vo = ((2 * t + (g >> 1)) ^ (c & 7)) * 8 + (g & 1) * 4;
#pragma unroll
      for (int dt = 0; dt < 4; dt++) {
        half4 va = *(const half4*)&sV[buf][(dt * 16 + c) * 64 + vo];
        zacc[0][dt] = MFMA16(va, b0.h, zacc[0][dt]);
        zacc[1][dt] = MFMA16(va, b1.h, zacc[1][dt]);
      }
    }
    __builtin_amdgcn_s_setprio(0);
  };

  // prologue
  stage(0, 0);
  asm volatile("s_waitcnt vmcnt(0)" ::: "memory");
  __builtin_amdgcn_s_barrier();

  // 32 tiles, double-buffered 2-step unroll
#pragma unroll 1
  for (int t2 = 0; t2 < 16; t2++) {
    {
      stage(1, 2 * t2 + 1);
      compute(0);
      asm volatile("s_waitcnt vmcnt(0) lgkmcnt(0)" ::: "memory");
      __builtin_amdgcn_s_barrier();
    }
    {
      const int nxt = 2 * t2 + 2;
      stage(0, nxt < 32 ? nxt : 31);  // clamp (last restages 31, unused)
      compute(1);
      asm volatile("s_waitcnt vmcnt(0) lgkmcnt(0)" ::: "memory");
      __builtin_amdgcn_s_barrier();
    }
  }

  // epilogue: lacc[qi][0] already holds the full row sum (MFMA k-reduce)
  const int qg0 = qblk * 128 + w * 32 + c;
#pragma unroll
  for (int qi = 0; qi < 2; qi++) {
    const float rs = lacc[qi][0];
    const float inv = rs > 0.f ? 1.0f / rs : 0.f;
    const int qg = qg0 + qi * 16;
#pragma unroll
    for (int dt = 0; dt < 4; dt++) {
      u32x2 zw;
      zw[0] = pkhf(zacc[qi][dt][0] * inv, zacc[qi][dt][1] * inv);
      zw[1] = pkhf(zacc[qi][dt][2] * inv, zacc[qi][dt][3] * inv);
      *reinterpret_cast<u32x2*>(
          &Z[(size_t)(b * 2048 + qg) * 1024 + h * 64 + dt * 16 + g * 4]) = zw;
    }
  }
}

// ---------- output projection GEMM (fp16, BK=64) ----------
// out[m,n] = sum_k Z[m,k]*Wo[n,k] + bo[n]. grid 512 linear, XCD-swizzled.
__global__ __launch_bounds__(256) void gemm_out(
    const short* __restrict__ Zb, const short* __restrict__ Wof,
    const float* __restrict__ bo, float* __restrict__ out) {
  __shared__ short sA[128 * 64], sB[128 * 64];
  const int tid = threadIdx.x, lane = tid & 63, w = tid >> 6;
  const int wr = w >> 1, wc = w & 1;
  const int g = lane >> 4, c = lane & 15;
  const int L = blockIdx.x;
  const int m0 = (L >> 3) * 128, n0 = (L & 7) * 128;

  f32x4 acc[4][4];
#pragma unroll
  for (int i = 0; i < 4; i++)
#pragma unroll
    for (int j = 0; j < 4; j++) acc[i][j] = (f32x4){0.f, 0.f, 0.f, 0.f};

  const int sw0 = ((0 * 4 + g) ^ (c & 7)) * 8;
  const int sw1 = ((1 * 4 + g) ^ (c & 7)) * 8;

  for (int ks = 0; ks < 16; ks++) {
    const int k0 = ks * 64;
    __syncthreads();
#pragma unroll
    for (int i = 0; i < 4; i++) {
      const int ch = i * 256 + tid;
      const int row = ch >> 3;
      const int colg = (ch & 7) ^ (row & 7);
      const size_t aoff = (size_t)(m0 + row) * 1024 + k0 + colg * 8;
      const size_t boff = (size_t)(n0 + row) * 1024 + k0 + colg * 8;
      GLD16(Zb + aoff, (char*)sA + ch * 16);
      GLD16(Wof + boff, (char*)sB + ch * 16);
    }
    asm volatile("s_waitcnt vmcnt(0)" ::: "memory");
    __syncthreads();

#pragma unroll
    for (int cc = 0; cc < 2; cc++) {
      const int sw = cc ? sw1 : sw0;
      half8 a[4], b8[4];
#pragma unroll
      for (int i = 0; i < 4; i++) {
        a[i] = *(const half8*)&sA[(wr * 64 + i * 16 + c) * 64 + sw];
        b8[i] = *(const half8*)&sB[(wc * 64 + i * 16 + c) * 64 + sw];
      }
#pragma unroll
      for (int i = 0; i < 4; i++)
#pragma unroll
        for (int j = 0; j < 4; j++)
          acc[i][j] = MFMA_F16(a[i], b8[j], acc[i][j]);
    }
  }

#pragma unroll
  for (int i = 0; i < 4; i++)
#pragma unroll
    for (int j = 0; j < 4; j++)
#pragma unroll
      for (int r = 0; r < 4; r++) {
        const int m = m0 + wr * 64 + i * 16 + g * 4 + r;
        const int n = n0 + wc * 64 + j * 16 + c;
        out[(size_t)m * 1024 + n] = acc[i][j][r] + bo[n];
      }
}

// ---------- host ----------
extern "C" void kernel_launch(void* const* d_in, const int* in_sizes, int n_in,
                              void* d_out, int out_size, void* d_ws, size_t ws_size,
                              hipStream_t stream) {
  const float* x  = (const float*)d_in[0];
  const float* Wq = (const float*)d_in[1];
  const float* Wk = (const float*)d_in[2];
  const float* Wv = (const float*)d_in[3];
  const float* Wo = (const float*)d_in[4];
  const float* bo = (const float*)d_in[5];
  float* out = (float*)d_out;

  const size_t NX = 8388608;   // B*S*D_MODEL
  const size_t NW = 1048576;   // per-projection weight elements
  const size_t NQ = 8388608;   // B*H*S*D_K

  char* p = (char*)d_ws;
  auto take = [&](size_t bytes) -> char* {
    char* r = p;
    p += (bytes + 255) & ~(size_t)255;
    return r;
  };
  short* Xf  = (short*)take(NX * 2);
  short* Wf  = (short*)take(3 * NW * 2);
  short* Wof = (short*)take(NW * 2);
  short* Qf  = (short*)take(NQ * 2);
  short* Kf  = (short*)take(NQ * 2);
  short* Vt  = (short*)take(NQ * 2);
  short* Zb  = (short*)take(NQ * 2);

  cast_all<<<dim3(12288), 256, 0, stream>>>(x, Wq, Wk, Wv, Wo, Xf, Wf, Wof);
  gemm_proj<<<dim3(1536), 256, 0, stream>>>(Xf, Wf, Qf, Kf, Vt);
  attn_kernel<<<dim3(1024), 256, 0, stream>>>(Qf, Kf, Vt, Zb);
  gemm_out<<<dim3(512), 256, 0, stream>>>(Zb, Wof, bo, out);
}